// Round 3
// baseline (2590.388 us; speedup 1.0000x reference)
//
#include <hip/hip_runtime.h>
#include <math.h>

typedef long long i64;

#define GWD 1024
#define GMSK 1023
#define GSH 10

__device__ __forceinline__ int nbrs_of(int m, int* nb) {
  int xx = m & GMSK, yy = m >> GSH;
  int c = 0;
  if (xx > 0)    nb[c++] = m - 1;
  if (xx < GMSK) nb[c++] = m + 1;
  if (yy > 0)    nb[c++] = m - GWD;
  if (yy < GMSK) nb[c++] = m + GWD;
  return c;
}

__device__ __forceinline__ int deg_of(int m) {
  int xx = m & GMSK, yy = m >> GSH;
  return (xx > 0) + (xx < GMSK) + (yy > 0) + (yy < GMSK);
}

// ---- level-1 matching: partner1[i] = min-index argmax_j w(i,j), gather only
__global__ __launch_bounds__(256)
void k_match1(const float* __restrict__ x, int* __restrict__ partner1, int n1) {
#pragma clang fp contract(off)
  int i = blockIdx.x * blockDim.x + threadIdx.x;
  if (i >= n1) return;
  float xi = x[(i64)i * 5];
  float invi = 1.0f / (float)deg_of(i);
  int nb[4];
  int cnt = nbrs_of(i, nb);
  float best = -INFINITY;
  int pr = n1;
  for (int t = 0; t < cnt; ++t) {
    int j = nb[t];
    float w = fabsf(xi - x[(i64)j * 5]) * (invi + 1.0f / (float)deg_of(j));
    if (w > best) { best = w; pr = j; }
    else if (w == best && j < pr) pr = j;
  }
  partner1[i] = (pr >= n1) ? i : pr;
}

__global__ __launch_bounds__(256)
void k_cluster1(const int* __restrict__ partner1, int* __restrict__ c1, int n1) {
  int i = blockIdx.x * blockDim.x + threadIdx.x;
  if (i >= n1) return;
  int p = partner1[i];
  c1[i] = (partner1[p] == i) ? min(i, p) : i;
}

// conv1 for one node: relu( mean_nb(x_j) @ W1 + x_m @ W1r + b1 )
__device__ __forceinline__ void conv1_eval(const float* __restrict__ x, int m,
                                           const float* w1, const float* w1r,
                                           const float* b1, float* out) {
  int nb[4];
  int cnt = nbrs_of(m, nb);
  float s[5] = {0.f, 0.f, 0.f, 0.f, 0.f};
  for (int t = 0; t < cnt; ++t) {
    const float* xj = x + (i64)nb[t] * 5;
#pragma unroll
    for (int k = 0; k < 5; ++k) s[k] += xj[k];
  }
  float xm[5];
#pragma unroll
  for (int k = 0; k < 5; ++k) xm[k] = x[(i64)m * 5 + k];
  float cf = (float)cnt;
#pragma unroll
  for (int f = 0; f < 16; ++f) {
    float a = 0.f, rt = 0.f;
#pragma unroll
    for (int k = 0; k < 5; ++k) {
      a  += s[k]  * w1[k * 16 + f];
      rt += xm[k] * w1r[k * 16 + f];
    }
    out[f] = fmaxf(a / cf + rt + b1[f], 0.0f);
  }
}

// ---- pool1 (heads only): xp = max over members of conv1; posp = centroid; deg2 = coarse out-degree
__global__ __launch_bounds__(256)
void k_pool1(const float* __restrict__ x, const float* __restrict__ pos,
             const int* __restrict__ partner1, const int* __restrict__ c1,
             const float* __restrict__ W1, const float* __restrict__ W1r,
             const float* __restrict__ b1,
             float* __restrict__ xp, float* __restrict__ posp,
             int* __restrict__ deg2, int n1) {
  __shared__ float w1s[80], w1rs[80], b1s[16];
  for (int t = threadIdx.x; t < 80; t += blockDim.x) { w1s[t] = W1[t]; w1rs[t] = W1r[t]; }
  if (threadIdx.x < 16) b1s[threadIdx.x] = b1[threadIdx.x];
  __syncthreads();
  int i = blockIdx.x * blockDim.x + threadIdx.x;
  if (i >= n1) return;
  if (c1[i] != i) return;  // heads only
  int p = partner1[i];
  bool pair = (p != i) && (partner1[p] == i);

  float v[16];
  conv1_eval(x, i, w1s, w1rs, b1s, v);
  if (pair) {
    float u[16];
    conv1_eval(x, p, w1s, w1rs, b1s, u);
#pragma unroll
    for (int f = 0; f < 16; ++f) v[f] = fmaxf(v[f], u[f]);
  }
#pragma unroll
  for (int f = 0; f < 16; ++f) xp[(i64)i * 16 + f] = v[f];

  float px = pos[(i64)i * 2], py = pos[(i64)i * 2 + 1];
  if (pair) {
    px = (px + pos[(i64)p * 2]) * 0.5f;
    py = (py + pos[(i64)p * 2 + 1]) * 0.5f;
  }
  posp[(i64)i * 2] = px;
  posp[(i64)i * 2 + 1] = py;

  // coarse out-degree (with multiplicity)
  int d = 0;
  int mem[2]; mem[0] = i; mem[1] = p;
  int nm = pair ? 2 : 1;
  for (int t = 0; t < nm; ++t) {
    int nb[4];
    int cn = nbrs_of(mem[t], nb);
    for (int u = 0; u < cn; ++u)
      if (c1[nb[u]] != i) ++d;
  }
  deg2[i] = d;
}

// ---- level-2 matching over coarse edges (heads only)
__global__ __launch_bounds__(256)
void k_match2(const int* __restrict__ partner1, const int* __restrict__ c1,
              const float* __restrict__ posp, const int* __restrict__ deg2,
              int* __restrict__ partner2, int n1) {
#pragma clang fp contract(off)
  int i = blockIdx.x * blockDim.x + threadIdx.x;
  if (i >= n1) return;
  if (c1[i] != i) return;
  int p = partner1[i];
  bool pair = (p != i) && (partner1[p] == i);
  float pix = posp[(i64)i * 2], piy = posp[(i64)i * 2 + 1];
  int di = deg2[i];
  float invi = (di > 0) ? 1.0f / (float)di : 0.0f;
  float best = -INFINITY;
  int pr = n1;
  int mem[2]; mem[0] = i; mem[1] = p;
  int nm = pair ? 2 : 1;
  for (int t = 0; t < nm; ++t) {
    int nb[4];
    int cn = nbrs_of(mem[t], nb);
    for (int u = 0; u < cn; ++u) {
      int cu = c1[nb[u]];
      if (cu == i) continue;
      float dx = pix - posp[(i64)cu * 2];
      float dy = piy - posp[(i64)cu * 2 + 1];
      float attr = sqrtf((dx * dx + dy * dy) + 1e-12f);
      int dc = deg2[cu];
      float invc = (dc > 0) ? 1.0f / (float)dc : 0.0f;
      float w = attr * (invi + invc);
      if (w > best) { best = w; pr = cu; }
      else if (w == best && cu < pr) pr = cu;
    }
  }
  partner2[i] = (pr >= n1) ? i : pr;
}

// conv2 for one level-1 head h: relu( mean_extern(xp_cu) @ W2 + xp_h @ W2r + b2 )
__device__ __forceinline__ void conv2_eval(const float* __restrict__ xp,
                                           const int* __restrict__ partner1,
                                           const int* __restrict__ c1, int h,
                                           const float* w2, const float* w2r,
                                           const float* b2, float* out) {
  float s[16];
#pragma unroll
  for (int k = 0; k < 16; ++k) s[k] = 0.f;
  int cnt = 0;
  int p = partner1[h];
  bool pair = (p != h) && (partner1[p] == h);
  int mem[2]; mem[0] = h; mem[1] = p;
  int nm = pair ? 2 : 1;
  for (int t = 0; t < nm; ++t) {
    int nb[4];
    int cn = nbrs_of(mem[t], nb);
    for (int u = 0; u < cn; ++u) {
      int cu = c1[nb[u]];
      if (cu == h) continue;
      ++cnt;
      const float* xq = xp + (i64)cu * 16;
#pragma unroll
      for (int k = 0; k < 16; ++k) s[k] += xq[k];
    }
  }
  const float* xh = xp + (i64)h * 16;
  float cf = (float)max(cnt, 1);
#pragma unroll
  for (int f = 0; f < 32; ++f) {
    float a = 0.f, rt = 0.f;
#pragma unroll
    for (int k = 0; k < 16; ++k) {
      a  += s[k]  * w2[k * 32 + f];
      rt += xh[k] * w2r[k * 32 + f];
    }
    out[f] = fmaxf(a / cf + rt + b2[f], 0.0f);
  }
}

// ---- pool2 + partial reduction: per level-2 head, x3 = max over members of conv2; block-reduce
__global__ __launch_bounds__(256)
void k_pool2reduce(const int* __restrict__ partner1, const int* __restrict__ c1,
                   const int* __restrict__ partner2,
                   const float* __restrict__ xp,
                   const float* __restrict__ W2, const float* __restrict__ W2r,
                   const float* __restrict__ b2,
                   float* __restrict__ partials, int n1) {
  __shared__ float w2s[512], w2rs[512], b2s[32];
  for (int t = threadIdx.x; t < 512; t += blockDim.x) { w2s[t] = W2[t]; w2rs[t] = W2r[t]; }
  if (threadIdx.x < 32) b2s[threadIdx.x] = b2[threadIdx.x];
  __syncthreads();

  int i = blockIdx.x * blockDim.x + threadIdx.x;
  float x3[32];
#pragma unroll
  for (int f = 0; f < 32; ++f) x3[f] = 0.f;
  float flag = 0.f;

  if (i < n1 && c1[i] == i) {
    int p2 = partner2[i];
    bool mut2 = (p2 != i) && (partner2[p2] == i);
    if (!(mut2 && p2 < i)) {  // level-2 head
      conv2_eval(xp, partner1, c1, i, w2s, w2rs, b2s, x3);
      if (mut2) {
        float u[32];
        conv2_eval(xp, partner1, c1, p2, w2s, w2rs, b2s, u);
#pragma unroll
        for (int f = 0; f < 32; ++f) x3[f] = fmaxf(x3[f], u[f]);
      }
      flag = 1.f;
    }
  }

  // deterministic block reduction of 33 values
  __shared__ float sm[4 * 33];
  int lane = threadIdx.x & 63, wv = threadIdx.x >> 6;
#pragma unroll
  for (int f = 0; f < 32; ++f) {
    float v = x3[f];
    for (int o = 32; o > 0; o >>= 1) v += __shfl_down(v, o, 64);
    if (lane == 0) sm[wv * 33 + f] = v;
  }
  {
    float v = flag;
    for (int o = 32; o > 0; o >>= 1) v += __shfl_down(v, o, 64);
    if (lane == 0) sm[wv * 33 + 32] = v;
  }
  __syncthreads();
  if (threadIdx.x < 33) {
    float v = sm[threadIdx.x] + sm[33 + threadIdx.x] + sm[66 + threadIdx.x] + sm[99 + threadIdx.x];
    partials[(i64)threadIdx.x * gridDim.x + blockIdx.x] = v;
  }
}

__global__ __launch_bounds__(64)
void k_final(const float* __restrict__ partials, int NB,
             const float* __restrict__ lin1w, const float* __restrict__ lin1b,
             const float* __restrict__ lin2w, const float* __restrict__ lin2b,
             float* __restrict__ out) {
  // 33 rows x NB cols; rows summed serially (deterministic), then tiny MLP
  __shared__ float tot[33];
  int t = threadIdx.x;
  if (t < 33) {
    const float* p = partials + (i64)t * NB;
    float a = 0.f;
    for (int b = 0; b < NB; ++b) a += p[b];
    tot[t] = a;
  }
  __syncthreads();
  if (t == 0) {
    float cnt = tot[32];
    float pooled[32];
    for (int f = 0; f < 32; ++f) pooled[f] = tot[f] / cnt;
    float h[8];
    for (int j = 0; j < 8; ++j) {
      float a = 0.f;
      for (int k = 0; k < 32; ++k) a += pooled[k] * lin1w[k * 8 + j];
      a += lin1b[j];
      h[j] = a >= 0.f ? a : 0.1f * a;
    }
    for (int m = 0; m < 2; ++m) {
      float a = 0.f;
      for (int j = 0; j < 8; ++j) a += h[j] * lin2w[j * 2 + m];
      out[m] = a + lin2b[m];
    }
  }
}

extern "C" void kernel_launch(void* const* d_in, const int* in_sizes, int n_in,
                              void* d_out, int out_size, void* d_ws, size_t ws_size,
                              hipStream_t stream) {
  const float* x   = (const float*)d_in[0];
  const float* pos = (const float*)d_in[1];
  const float* W1  = (const float*)d_in[3];
  const float* W1r = (const float*)d_in[4];
  const float* b1  = (const float*)d_in[5];
  const float* W2  = (const float*)d_in[6];
  const float* W2r = (const float*)d_in[7];
  const float* b2  = (const float*)d_in[8];
  const float* l1w = (const float*)d_in[9];
  const float* l1b = (const float*)d_in[10];
  const float* l2w = (const float*)d_in[11];
  const float* l2b = (const float*)d_in[12];
  float* out = (float*)d_out;

  const int n = in_sizes[0] / 5;  // 1048576 (1024x1024 grid)
  const int B = 256;
  const int gn = (n + B - 1) / B;  // 4096

  // workspace layout: 16n + 2n floats + 4n ints + 33*gn floats  ~= 93 MB
  float* base = (float*)d_ws;
  i64 off = 0;
  float* xp       = base + off; off += (i64)16 * n;
  float* posp     = base + off; off += (i64)2 * n;
  int*   partner1 = (int*)(base + off); off += n;
  int*   c1       = (int*)(base + off); off += n;
  int*   deg2     = (int*)(base + off); off += n;
  int*   partner2 = (int*)(base + off); off += n;
  float* partials = base + off; off += (i64)33 * gn;
  (void)ws_size; (void)n_in; (void)out_size;

  k_match1<<<gn, B, 0, stream>>>(x, partner1, n);
  k_cluster1<<<gn, B, 0, stream>>>(partner1, c1, n);
  k_pool1<<<gn, B, 0, stream>>>(x, pos, partner1, c1, W1, W1r, b1, xp, posp, deg2, n);
  k_match2<<<gn, B, 0, stream>>>(partner1, c1, posp, deg2, partner2, n);
  k_pool2reduce<<<gn, B, 0, stream>>>(partner1, c1, partner2, xp, W2, W2r, b2, partials, n);
  k_final<<<1, 64, 0, stream>>>(partials, gn, l1w, l1b, l2w, l2b, out);
}

// Round 4
// 1455.586 us; speedup vs baseline: 1.7796x; 1.7796x over previous
//
#include <hip/hip_runtime.h>
#include <math.h>

typedef long long i64;

#define GWD 1024
#define GMSK 1023
#define GSH 10

__device__ __forceinline__ int deg_of(int m) {
  int xx = m & GMSK, yy = m >> GSH;
  return (xx > 0) + (xx < GMSK) + (yy > 0) + (yy < GMSK);
}

// ============ A: level-1 matching, fully static neighbor slots ============
__global__ __launch_bounds__(256)
void kA_match1(const float* __restrict__ x, int* __restrict__ partner1, int n) {
#pragma clang fp contract(off)
  int m = blockIdx.x * 256 + threadIdx.x;
  if (m >= n) return;
  int xx = m & GMSK, yy = m >> GSH;
  bool vW = xx > 0, vE = xx < GMSK, vN = yy > 0, vS = yy < GMSK;
  int cnt = (int)vW + (int)vE + (int)vN + (int)vS;
  float invi = 1.0f / (float)cnt;
  float xm0 = x[(i64)m * 5];
  float best = -INFINITY;
  int pr = n;
  // visit in increasing index order: ties keep smallest index
#define NB1(valid, J)                                                  \
  if (valid) {                                                         \
    int j = (J);                                                       \
    float a0 = x[(i64)j * 5];                                          \
    float w = fabsf(xm0 - a0) * (invi + 1.0f / (float)deg_of(j));      \
    if (w > best) { best = w; pr = j; }                                \
  }
  NB1(vN, m - GWD)
  NB1(vW, m - 1)
  NB1(vE, m + 1)
  NB1(vS, m + GWD)
#undef NB1
  partner1[m] = pr;
}

// ============ B: c1, pooled features (replicated), centroids (replicated) ============
__device__ __forceinline__ void conv1_static(const float* __restrict__ x, int m,
                                             const float* w1, const float* w1r,
                                             const float* b1, float (&out)[16]) {
  int xx = m & GMSK, yy = m >> GSH;
  bool vW = xx > 0, vE = xx < GMSK, vN = yy > 0, vS = yy < GMSK;
  int cnt = (int)vW + (int)vE + (int)vN + (int)vS;
  float s0 = 0.f, s1 = 0.f, s2 = 0.f, s3 = 0.f, s4 = 0.f;
#define ACC1(valid, J)                                     \
  if (valid) {                                             \
    const float* xj = x + (i64)(J) * 5;                    \
    s0 += xj[0]; s1 += xj[1]; s2 += xj[2];                 \
    s3 += xj[3]; s4 += xj[4];                              \
  }
  ACC1(vN, m - GWD)
  ACC1(vW, m - 1)
  ACC1(vE, m + 1)
  ACC1(vS, m + GWD)
#undef ACC1
  const float* xm = x + (i64)m * 5;
  float m0 = xm[0], m1 = xm[1], m2 = xm[2], m3 = xm[3], m4 = xm[4];
  float cf = (float)cnt;
#pragma unroll
  for (int f = 0; f < 16; ++f) {
    float a  = s0 * w1[f] + s1 * w1[16 + f] + s2 * w1[32 + f] + s3 * w1[48 + f] + s4 * w1[64 + f];
    float rt = m0 * w1r[f] + m1 * w1r[16 + f] + m2 * w1r[32 + f] + m3 * w1r[48 + f] + m4 * w1r[64 + f];
    out[f] = fmaxf(a / cf + rt + b1[f], 0.0f);
  }
}

__global__ __launch_bounds__(256)
void kB_pool1(const float* __restrict__ x, const float* __restrict__ pos,
              const int* __restrict__ partner1,
              const float* __restrict__ W1, const float* __restrict__ W1r,
              const float* __restrict__ b1,
              int* __restrict__ c1, float* __restrict__ xpf,
              float* __restrict__ pospf, int n) {
#pragma clang fp contract(off)
  __shared__ float w1s[80], w1rs[80], b1s[16];
  for (int t = threadIdx.x; t < 80; t += 256) { w1s[t] = W1[t]; w1rs[t] = W1r[t]; }
  if (threadIdx.x < 16) b1s[threadIdx.x] = b1[threadIdx.x];
  __syncthreads();
  int m = blockIdx.x * 256 + threadIdx.x;
  if (m >= n) return;
  int p = partner1[m];
  bool mut = (partner1[p] == m);
  c1[m] = mut ? min(m, p) : m;

  float px = pos[(i64)m * 2], py = pos[(i64)m * 2 + 1];
  if (mut) {
    px = (px + pos[(i64)p * 2]) * 0.5f;
    py = (py + pos[(i64)p * 2 + 1]) * 0.5f;
  }
  pospf[(i64)m * 2] = px;
  pospf[(i64)m * 2 + 1] = py;

  float v[16];
  conv1_static(x, m, w1s, w1rs, b1s, v);
  if (mut) {
    float u[16];
    conv1_static(x, p, w1s, w1rs, b1s, u);
#pragma unroll
    for (int f = 0; f < 16; ++f) v[f] = fmaxf(v[f], u[f]);
  }
#pragma unroll
  for (int f = 0; f < 16; ++f) xpf[(i64)m * 16 + f] = v[f];
}

// ============ C: coarse degree (replicated per node) ============
__device__ __forceinline__ int dcount(const int* __restrict__ c1, int q, int cq) {
  int xx = q & GMSK, yy = q >> GSH;
  int d = 0;
  if (yy > 0    && c1[q - GWD] != cq) ++d;
  if (xx > 0    && c1[q - 1]   != cq) ++d;
  if (xx < GMSK && c1[q + 1]   != cq) ++d;
  if (yy < GMSK && c1[q + GWD] != cq) ++d;
  return d;
}

__global__ __launch_bounds__(256)
void kC_deg2(const int* __restrict__ partner1, const int* __restrict__ c1,
             int* __restrict__ deg2f, int n) {
  int m = blockIdx.x * 256 + threadIdx.x;
  if (m >= n) return;
  int cm = c1[m];
  int p = partner1[m];
  bool mut = (partner1[p] == m);
  int d = dcount(c1, m, cm);
  if (mut) d += dcount(c1, p, cm);
  deg2f[m] = d;
}

// ============ D: level-2 matching (heads only), static 8 slots ============
__global__ __launch_bounds__(256)
void kD_match2(const int* __restrict__ partner1, const int* __restrict__ c1,
               const float* __restrict__ pospf, const int* __restrict__ deg2f,
               int* __restrict__ partner2, int n) {
#pragma clang fp contract(off)
  int i = blockIdx.x * 256 + threadIdx.x;
  if (i >= n) return;
  if (c1[i] != i) return;  // heads only
  int p = partner1[i];
  bool mut = (partner1[p] == i);
  float pix = pospf[(i64)i * 2], piy = pospf[(i64)i * 2 + 1];
  int di = deg2f[i];
  float invi = (di > 0) ? 1.0f / (float)di : 0.0f;
  float best = -INFINITY;
  int bc = n;
#define NB2(valid, J)                                                   \
  if (valid) {                                                          \
    int j = (J);                                                        \
    int cu = c1[j];                                                     \
    if (cu != i) {                                                      \
      float dx = pix - pospf[(i64)j * 2];                               \
      float dy = piy - pospf[(i64)j * 2 + 1];                           \
      float attr = sqrtf((dx * dx + dy * dy) + 1e-12f);                 \
      int dc = deg2f[j];                                                \
      float invc = (dc > 0) ? 1.0f / (float)dc : 0.0f;                  \
      float w = attr * (invi + invc);                                   \
      if (w > best) { best = w; bc = cu; }                              \
      else if (w == best && cu < bc) bc = cu;                           \
    }                                                                   \
  }
  {
    int xx = i & GMSK, yy = i >> GSH;
    NB2(yy > 0, i - GWD)
    NB2(xx > 0, i - 1)
    NB2(xx < GMSK, i + 1)
    NB2(yy < GMSK, i + GWD)
  }
  if (mut) {
    int qx = p & GMSK, qy = p >> GSH;
    NB2(qy > 0, p - GWD)
    NB2(qx > 0, p - 1)
    NB2(qx < GMSK, p + 1)
    NB2(qy < GMSK, p + GWD)
  }
#undef NB2
  partner2[i] = (bc >= n) ? i : bc;
}

// ============ E: conv2 + pool2 + block reduction ============
__device__ __forceinline__ void accum_slot(const int* __restrict__ c1,
                                           const float* __restrict__ xpf,
                                           int j, int h, float (&s)[16], int& cnt) {
  if (c1[j] != h) {
    ++cnt;
    const float* xq = xpf + (i64)j * 16;
#pragma unroll
    for (int k = 0; k < 16; ++k) s[k] += xq[k];
  }
}

__device__ __forceinline__ void conv2_static(const int* __restrict__ partner1,
                                             const int* __restrict__ c1,
                                             const float* __restrict__ xpf,
                                             int h, const float* w2, const float* w2r,
                                             const float* b2, float (&out)[32], bool domax) {
  float s[16];
#pragma unroll
  for (int k = 0; k < 16; ++k) s[k] = 0.f;
  int cnt = 0;
  int ph = partner1[h];
  bool muth = (partner1[ph] == h);
  {
    int hx = h & GMSK, hy = h >> GSH;
    if (hy > 0)    accum_slot(c1, xpf, h - GWD, h, s, cnt);
    if (hx > 0)    accum_slot(c1, xpf, h - 1,   h, s, cnt);
    if (hx < GMSK) accum_slot(c1, xpf, h + 1,   h, s, cnt);
    if (hy < GMSK) accum_slot(c1, xpf, h + GWD, h, s, cnt);
  }
  if (muth) {
    int qx = ph & GMSK, qy = ph >> GSH;
    if (qy > 0)    accum_slot(c1, xpf, ph - GWD, h, s, cnt);
    if (qx > 0)    accum_slot(c1, xpf, ph - 1,   h, s, cnt);
    if (qx < GMSK) accum_slot(c1, xpf, ph + 1,   h, s, cnt);
    if (qy < GMSK) accum_slot(c1, xpf, ph + GWD, h, s, cnt);
  }
  float xh[16];
#pragma unroll
  for (int k = 0; k < 16; ++k) xh[k] = xpf[(i64)h * 16 + k];
  float cf = (float)(cnt > 1 ? cnt : 1);
#pragma unroll
  for (int f = 0; f < 32; ++f) {
    float a = 0.f, rt = 0.f;
#pragma unroll
    for (int k = 0; k < 16; ++k) {
      a  += s[k]  * w2[k * 32 + f];
      rt += xh[k] * w2r[k * 32 + f];
    }
    float val = fmaxf(a / cf + rt + b2[f], 0.0f);
    out[f] = domax ? fmaxf(out[f], val) : val;
  }
}

__global__ __launch_bounds__(256)
void kE_conv2_reduce(const int* __restrict__ partner1, const int* __restrict__ c1,
                     const int* __restrict__ partner2, const float* __restrict__ xpf,
                     const float* __restrict__ W2, const float* __restrict__ W2r,
                     const float* __restrict__ b2,
                     float* __restrict__ partials, int n) {
  __shared__ float w2s[512], w2rs[512], b2s[32];
  for (int t = threadIdx.x; t < 512; t += 256) { w2s[t] = W2[t]; w2rs[t] = W2r[t]; }
  if (threadIdx.x < 32) b2s[threadIdx.x] = b2[threadIdx.x];
  __syncthreads();

  int i = blockIdx.x * 256 + threadIdx.x;
  float x3[32];
#pragma unroll
  for (int f = 0; f < 32; ++f) x3[f] = 0.f;
  float flag = 0.f;

  if (i < n && c1[i] == i) {
    int p2 = partner2[i];
    bool mut2 = (p2 != i) && (partner2[p2] == i);
    if (!(mut2 && p2 < i)) {  // level-2 head
      flag = 1.f;
      conv2_static(partner1, c1, xpf, i, w2s, w2rs, b2s, x3, false);
      if (mut2) conv2_static(partner1, c1, xpf, p2, w2s, w2rs, b2s, x3, true);
    }
  }

  // deterministic block reduction of 33 values
  __shared__ float sm[4 * 33];
  int lane = threadIdx.x & 63, wv = threadIdx.x >> 6;
#pragma unroll
  for (int f = 0; f < 32; ++f) {
    float v = x3[f];
    for (int o = 32; o > 0; o >>= 1) v += __shfl_down(v, o, 64);
    if (lane == 0) sm[wv * 33 + f] = v;
  }
  {
    float v = flag;
    for (int o = 32; o > 0; o >>= 1) v += __shfl_down(v, o, 64);
    if (lane == 0) sm[wv * 33 + 32] = v;
  }
  __syncthreads();
  if (threadIdx.x < 33) {
    float v = sm[threadIdx.x] + sm[33 + threadIdx.x] + sm[66 + threadIdx.x] + sm[99 + threadIdx.x];
    partials[(i64)threadIdx.x * gridDim.x + blockIdx.x] = v;
  }
}

// ============ F: final reduce + MLP head ============
__global__ __launch_bounds__(256)
void k_final(const float* __restrict__ partials, int NB,
             const float* __restrict__ lin1w, const float* __restrict__ lin1b,
             const float* __restrict__ lin2w, const float* __restrict__ lin2b,
             float* __restrict__ out) {
  __shared__ float acc[33][4];
  __shared__ float tot[33];
  int t = threadIdx.x;
  int r = t >> 2, q = t & 3;
  int chunk = NB / 4;
  if (r < 33) {
    const float* pp = partials + (i64)r * NB + (i64)q * chunk;
    float a = 0.f;
    for (int b = 0; b < chunk; ++b) a += pp[b];
    acc[r][q] = a;
  }
  __syncthreads();
  if (t < 33) tot[t] = acc[t][0] + acc[t][1] + acc[t][2] + acc[t][3];
  __syncthreads();
  if (t == 0) {
    float cnt = tot[32];
    float pooled[32];
    for (int f = 0; f < 32; ++f) pooled[f] = tot[f] / cnt;
    float h[8];
    for (int j = 0; j < 8; ++j) {
      float a = 0.f;
      for (int k = 0; k < 32; ++k) a += pooled[k] * lin1w[k * 8 + j];
      a += lin1b[j];
      h[j] = a >= 0.f ? a : 0.1f * a;
    }
    for (int m = 0; m < 2; ++m) {
      float a = 0.f;
      for (int j = 0; j < 8; ++j) a += h[j] * lin2w[j * 2 + m];
      out[m] = a + lin2b[m];
    }
  }
}

extern "C" void kernel_launch(void* const* d_in, const int* in_sizes, int n_in,
                              void* d_out, int out_size, void* d_ws, size_t ws_size,
                              hipStream_t stream) {
  const float* x   = (const float*)d_in[0];
  const float* pos = (const float*)d_in[1];
  const float* W1  = (const float*)d_in[3];
  const float* W1r = (const float*)d_in[4];
  const float* b1  = (const float*)d_in[5];
  const float* W2  = (const float*)d_in[6];
  const float* W2r = (const float*)d_in[7];
  const float* b2  = (const float*)d_in[8];
  const float* l1w = (const float*)d_in[9];
  const float* l1b = (const float*)d_in[10];
  const float* l2w = (const float*)d_in[11];
  const float* l2b = (const float*)d_in[12];
  float* out = (float*)d_out;

  const int n = in_sizes[0] / 5;  // 1048576
  const int B = 256;
  const int gn = (n + B - 1) / B;  // 4096

  // workspace: 16n (xpf) + 2n (pospf) + 4n ints + 33*gn  ≈ 88.5 MB
  float* base = (float*)d_ws;
  i64 off = 0;
  float* xpf      = base + off; off += (i64)16 * n;
  float* pospf    = base + off; off += (i64)2 * n;
  int*   partner1 = (int*)(base + off); off += n;
  int*   c1       = (int*)(base + off); off += n;
  int*   deg2f    = (int*)(base + off); off += n;
  int*   partner2 = (int*)(base + off); off += n;
  float* partials = base + off; off += (i64)33 * gn;
  (void)ws_size; (void)n_in; (void)out_size;

  kA_match1<<<gn, B, 0, stream>>>(x, partner1, n);
  kB_pool1<<<gn, B, 0, stream>>>(x, pos, partner1, W1, W1r, b1, c1, xpf, pospf, n);
  kC_deg2<<<gn, B, 0, stream>>>(partner1, c1, deg2f, n);
  kD_match2<<<gn, B, 0, stream>>>(partner1, c1, pospf, deg2f, partner2, n);
  kE_conv2_reduce<<<gn, B, 0, stream>>>(partner1, c1, partner2, xpf, W2, W2r, b2, partials, n);
  k_final<<<1, 256, 0, stream>>>(partials, gn, l1w, l1b, l2w, l2b, out);
}

// Round 5
// 325.600 us; speedup vs baseline: 7.9557x; 4.4705x over previous
//
#include <hip/hip_runtime.h>
#include <math.h>

typedef long long i64;

#define GWD 1024
#define GMSK 1023
#define GSH 10

__device__ __forceinline__ int deg_of(int m) {
  int xx = m & GMSK, yy = m >> GSH;
  return (xx > 0) + (xx < GMSK) + (yy > 0) + (yy < GMSK);
}

// ============ A: level-1 matching, fully static neighbor slots ============
__global__ __launch_bounds__(256)
void kA_match1(const float* __restrict__ x, int* __restrict__ partner1, int n) {
#pragma clang fp contract(off)
  int m = blockIdx.x * 256 + threadIdx.x;
  if (m >= n) return;
  int xx = m & GMSK, yy = m >> GSH;
  bool vW = xx > 0, vE = xx < GMSK, vN = yy > 0, vS = yy < GMSK;
  int cnt = (int)vW + (int)vE + (int)vN + (int)vS;
  float invi = 1.0f / (float)cnt;
  float xm0 = x[(i64)m * 5];
  float best = -INFINITY;
  int pr = n;
#define NB1(valid, J)                                                  \
  if (valid) {                                                         \
    int j = (J);                                                       \
    float a0 = x[(i64)j * 5];                                          \
    float w = fabsf(xm0 - a0) * (invi + 1.0f / (float)deg_of(j));      \
    if (w > best) { best = w; pr = j; }                                \
  }
  NB1(vN, m - GWD)
  NB1(vW, m - 1)
  NB1(vE, m + 1)
  NB1(vS, m + GWD)
#undef NB1
  partner1[m] = pr;
}

// ============ B: c1, pooled features (replicated), centroids (replicated) ============
__device__ __forceinline__ void conv1_static(const float* __restrict__ x, int m,
                                             const float* w1, const float* w1r,
                                             const float* b1, float (&out)[16]) {
  int xx = m & GMSK, yy = m >> GSH;
  bool vW = xx > 0, vE = xx < GMSK, vN = yy > 0, vS = yy < GMSK;
  int cnt = (int)vW + (int)vE + (int)vN + (int)vS;
  float s0 = 0.f, s1 = 0.f, s2 = 0.f, s3 = 0.f, s4 = 0.f;
#define ACC1(valid, J)                                     \
  if (valid) {                                             \
    const float* xj = x + (i64)(J) * 5;                    \
    s0 += xj[0]; s1 += xj[1]; s2 += xj[2];                 \
    s3 += xj[3]; s4 += xj[4];                              \
  }
  ACC1(vN, m - GWD)
  ACC1(vW, m - 1)
  ACC1(vE, m + 1)
  ACC1(vS, m + GWD)
#undef ACC1
  const float* xm = x + (i64)m * 5;
  float m0 = xm[0], m1 = xm[1], m2 = xm[2], m3 = xm[3], m4 = xm[4];
  float cf = (float)cnt;
#pragma unroll
  for (int f = 0; f < 16; ++f) {
    float a  = s0 * w1[f] + s1 * w1[16 + f] + s2 * w1[32 + f] + s3 * w1[48 + f] + s4 * w1[64 + f];
    float rt = m0 * w1r[f] + m1 * w1r[16 + f] + m2 * w1r[32 + f] + m3 * w1r[48 + f] + m4 * w1r[64 + f];
    out[f] = fmaxf(a / cf + rt + b1[f], 0.0f);
  }
}

__global__ __launch_bounds__(256)
void kB_pool1(const float* __restrict__ x, const float* __restrict__ pos,
              const int* __restrict__ partner1,
              const float* __restrict__ W1, const float* __restrict__ W1r,
              const float* __restrict__ b1,
              int* __restrict__ c1, float* __restrict__ xpf,
              float* __restrict__ pospf, int n) {
#pragma clang fp contract(off)
  __shared__ float w1s[80], w1rs[80], b1s[16];
  for (int t = threadIdx.x; t < 80; t += 256) { w1s[t] = W1[t]; w1rs[t] = W1r[t]; }
  if (threadIdx.x < 16) b1s[threadIdx.x] = b1[threadIdx.x];
  __syncthreads();
  int m = blockIdx.x * 256 + threadIdx.x;
  if (m >= n) return;
  int p = partner1[m];
  bool mut = (partner1[p] == m);
  c1[m] = mut ? min(m, p) : m;

  float px = pos[(i64)m * 2], py = pos[(i64)m * 2 + 1];
  if (mut) {
    px = (px + pos[(i64)p * 2]) * 0.5f;
    py = (py + pos[(i64)p * 2 + 1]) * 0.5f;
  }
  pospf[(i64)m * 2] = px;
  pospf[(i64)m * 2 + 1] = py;

  float v[16];
  conv1_static(x, m, w1s, w1rs, b1s, v);
  if (mut) {
    float u[16];
    conv1_static(x, p, w1s, w1rs, b1s, u);
#pragma unroll
    for (int f = 0; f < 16; ++f) v[f] = fmaxf(v[f], u[f]);
  }
#pragma unroll
  for (int f = 0; f < 16; ++f) xpf[(i64)m * 16 + f] = v[f];
}

// ============ C: coarse degree (replicated per node) ============
__device__ __forceinline__ int dcount(const int* __restrict__ c1, int q, int cq) {
  int xx = q & GMSK, yy = q >> GSH;
  int d = 0;
  if (yy > 0    && c1[q - GWD] != cq) ++d;
  if (xx > 0    && c1[q - 1]   != cq) ++d;
  if (xx < GMSK && c1[q + 1]   != cq) ++d;
  if (yy < GMSK && c1[q + GWD] != cq) ++d;
  return d;
}

__global__ __launch_bounds__(256)
void kC_deg2(const int* __restrict__ partner1, const int* __restrict__ c1,
             int* __restrict__ deg2f, int n) {
  int m = blockIdx.x * 256 + threadIdx.x;
  if (m >= n) return;
  int cm = c1[m];
  int p = partner1[m];
  bool mut = (partner1[p] == m);
  int d = dcount(c1, m, cm);
  if (mut) d += dcount(c1, p, cm);
  deg2f[m] = d;
}

// ============ D: level-2 matching (heads only), static 8 slots ============
__global__ __launch_bounds__(256)
void kD_match2(const int* __restrict__ partner1, const int* __restrict__ c1,
               const float* __restrict__ pospf, const int* __restrict__ deg2f,
               int* __restrict__ partner2, int n) {
#pragma clang fp contract(off)
  int i = blockIdx.x * 256 + threadIdx.x;
  if (i >= n) return;
  if (c1[i] != i) return;  // heads only
  int p = partner1[i];
  bool mut = (partner1[p] == i);
  float pix = pospf[(i64)i * 2], piy = pospf[(i64)i * 2 + 1];
  int di = deg2f[i];
  float invi = (di > 0) ? 1.0f / (float)di : 0.0f;
  float best = -INFINITY;
  int bc = n;
#define NB2(valid, J)                                                   \
  if (valid) {                                                          \
    int j = (J);                                                        \
    int cu = c1[j];                                                     \
    if (cu != i) {                                                      \
      float dx = pix - pospf[(i64)j * 2];                               \
      float dy = piy - pospf[(i64)j * 2 + 1];                           \
      float attr = sqrtf((dx * dx + dy * dy) + 1e-12f);                 \
      int dc = deg2f[j];                                                \
      float invc = (dc > 0) ? 1.0f / (float)dc : 0.0f;                  \
      float w = attr * (invi + invc);                                   \
      if (w > best) { best = w; bc = cu; }                              \
      else if (w == best && cu < bc) bc = cu;                           \
    }                                                                   \
  }
  {
    int xx = i & GMSK, yy = i >> GSH;
    NB2(yy > 0, i - GWD)
    NB2(xx > 0, i - 1)
    NB2(xx < GMSK, i + 1)
    NB2(yy < GMSK, i + GWD)
  }
  if (mut) {
    int qx = p & GMSK, qy = p >> GSH;
    NB2(qy > 0, p - GWD)
    NB2(qx > 0, p - 1)
    NB2(qx < GMSK, p + 1)
    NB2(qy < GMSK, p + GWD)
  }
#undef NB2
  partner2[i] = (bc >= n) ? i : bc;
}

// ============ E: conv2 + pool2 + block reduction — ZERO local arrays ============
#define DECL16(P) \
  float P##0=0.f,P##1=0.f,P##2=0.f,P##3=0.f,P##4=0.f,P##5=0.f,P##6=0.f,P##7=0.f, \
        P##8=0.f,P##9=0.f,P##10=0.f,P##11=0.f,P##12=0.f,P##13=0.f,P##14=0.f,P##15=0.f

#define LOAD16(P, ptr) do { const float* _q=(ptr); \
  P##0=_q[0]; P##1=_q[1]; P##2=_q[2]; P##3=_q[3]; P##4=_q[4]; P##5=_q[5]; P##6=_q[6]; P##7=_q[7]; \
  P##8=_q[8]; P##9=_q[9]; P##10=_q[10]; P##11=_q[11]; P##12=_q[12]; P##13=_q[13]; P##14=_q[14]; P##15=_q[15]; } while(0)

#define ADD16(P, ptr) do { const float* _q=(ptr); \
  P##0+=_q[0]; P##1+=_q[1]; P##2+=_q[2]; P##3+=_q[3]; P##4+=_q[4]; P##5+=_q[5]; P##6+=_q[6]; P##7+=_q[7]; \
  P##8+=_q[8]; P##9+=_q[9]; P##10+=_q[10]; P##11+=_q[11]; P##12+=_q[12]; P##13+=_q[13]; P##14+=_q[14]; P##15+=_q[15]; } while(0)

#define DOTW(P, W, f) \
  (P##0*(W)[(f)] + P##1*(W)[32+(f)] + P##2*(W)[64+(f)] + P##3*(W)[96+(f)] + \
   P##4*(W)[128+(f)] + P##5*(W)[160+(f)] + P##6*(W)[192+(f)] + P##7*(W)[224+(f)] + \
   P##8*(W)[256+(f)] + P##9*(W)[288+(f)] + P##10*(W)[320+(f)] + P##11*(W)[352+(f)] + \
   P##12*(W)[384+(f)] + P##13*(W)[416+(f)] + P##14*(W)[448+(f)] + P##15*(W)[480+(f)])

#define GATHER_MEMBER(P, CNT, m, cid) do {                                     \
  int _m = (m); int _mx = _m & GMSK, _my = _m >> GSH;                           \
  if (_my > 0)    { int _j = _m - GWD; if (c1[_j] != (cid)) { ++CNT; ADD16(P, xpf + (i64)_j * 16); } } \
  if (_mx > 0)    { int _j = _m - 1;   if (c1[_j] != (cid)) { ++CNT; ADD16(P, xpf + (i64)_j * 16); } } \
  if (_mx < GMSK) { int _j = _m + 1;   if (c1[_j] != (cid)) { ++CNT; ADD16(P, xpf + (i64)_j * 16); } } \
  if (_my < GMSK) { int _j = _m + GWD; if (c1[_j] != (cid)) { ++CNT; ADD16(P, xpf + (i64)_j * 16); } } \
} while(0)

__global__ __launch_bounds__(256)
void kE_conv2_reduce(const int* __restrict__ partner1, const int* __restrict__ c1,
                     const int* __restrict__ partner2, const float* __restrict__ xpf,
                     const float* __restrict__ W2, const float* __restrict__ W2r,
                     const float* __restrict__ b2,
                     float* __restrict__ partials, int n) {
  int i = blockIdx.x * 256 + threadIdx.x;
  bool active = false, mut2 = false;
  int p2 = 0;
  if (i < n && c1[i] == i) {
    p2 = partner2[i];
    mut2 = (p2 != i) && (partner2[p2] == i);
    active = !(mut2 && p2 < i);  // exactly one thread per level-2 cluster
  }

  DECL16(sA); DECL16(hA); int cntA = 0;
  DECL16(sB); DECL16(hB); int cntB = 0;
  if (active) {
    int pA = partner1[i];
    bool mA = (partner1[pA] == i);
    GATHER_MEMBER(sA, cntA, i, i);
    if (mA) GATHER_MEMBER(sA, cntA, pA, i);
    LOAD16(hA, xpf + (i64)i * 16);
    if (mut2) {
      int pB = partner1[p2];
      bool mB = (partner1[pB] == p2);
      GATHER_MEMBER(sB, cntB, p2, p2);
      if (mB) GATHER_MEMBER(sB, cntB, pB, p2);
      LOAD16(hB, xpf + (i64)p2 * 16);
    }
  }
  float cfA = (float)(cntA > 1 ? cntA : 1);
  float cfB = (float)(cntB > 1 ? cntB : 1);

  __shared__ float sm[4 * 33];
  int lane = threadIdx.x & 63, wv = threadIdx.x >> 6;

  for (int f = 0; f < 32; ++f) {  // f is wave-uniform: weight reads become scalar loads
    float val = 0.f;
    if (active) {
      float a  = DOTW(sA, W2, f);
      float rt = DOTW(hA, W2r, f);
      val = fmaxf(a / cfA + rt + b2[f], 0.0f);
      if (mut2) {
        float ab  = DOTW(sB, W2, f);
        float rtb = DOTW(hB, W2r, f);
        val = fmaxf(val, fmaxf(ab / cfB + rtb + b2[f], 0.0f));
      }
    }
    for (int o = 32; o > 0; o >>= 1) val += __shfl_down(val, o, 64);
    if (lane == 0) sm[wv * 33 + f] = val;
  }
  {
    float v = active ? 1.f : 0.f;
    for (int o = 32; o > 0; o >>= 1) v += __shfl_down(v, o, 64);
    if (lane == 0) sm[wv * 33 + 32] = v;
  }
  __syncthreads();
  if (threadIdx.x < 33) {
    float v = sm[threadIdx.x] + sm[33 + threadIdx.x] + sm[66 + threadIdx.x] + sm[99 + threadIdx.x];
    partials[(i64)threadIdx.x * gridDim.x + blockIdx.x] = v;
  }
}

// ============ F: final reduce + MLP head ============
__global__ __launch_bounds__(256)
void k_final(const float* __restrict__ partials, int NB,
             const float* __restrict__ lin1w, const float* __restrict__ lin1b,
             const float* __restrict__ lin2w, const float* __restrict__ lin2b,
             float* __restrict__ out) {
  __shared__ float acc[33][4];
  __shared__ float tot[33];
  int t = threadIdx.x;
  int r = t >> 2, q = t & 3;
  int chunk = NB / 4;
  if (r < 33) {
    const float* pp = partials + (i64)r * NB + (i64)q * chunk;
    float a = 0.f;
    for (int b = 0; b < chunk; ++b) a += pp[b];
    acc[r][q] = a;
  }
  __syncthreads();
  if (t < 33) tot[t] = acc[t][0] + acc[t][1] + acc[t][2] + acc[t][3];
  __syncthreads();
  if (t == 0) {
    float cnt = tot[32];
    float pooled[32];
    for (int f = 0; f < 32; ++f) pooled[f] = tot[f] / cnt;
    float h[8];
    for (int j = 0; j < 8; ++j) {
      float a = 0.f;
      for (int k = 0; k < 32; ++k) a += pooled[k] * lin1w[k * 8 + j];
      a += lin1b[j];
      h[j] = a >= 0.f ? a : 0.1f * a;
    }
    for (int m = 0; m < 2; ++m) {
      float a = 0.f;
      for (int j = 0; j < 8; ++j) a += h[j] * lin2w[j * 2 + m];
      out[m] = a + lin2b[m];
    }
  }
}

extern "C" void kernel_launch(void* const* d_in, const int* in_sizes, int n_in,
                              void* d_out, int out_size, void* d_ws, size_t ws_size,
                              hipStream_t stream) {
  const float* x   = (const float*)d_in[0];
  const float* pos = (const float*)d_in[1];
  const float* W1  = (const float*)d_in[3];
  const float* W1r = (const float*)d_in[4];
  const float* b1  = (const float*)d_in[5];
  const float* W2  = (const float*)d_in[6];
  const float* W2r = (const float*)d_in[7];
  const float* b2  = (const float*)d_in[8];
  const float* l1w = (const float*)d_in[9];
  const float* l1b = (const float*)d_in[10];
  const float* l2w = (const float*)d_in[11];
  const float* l2b = (const float*)d_in[12];
  float* out = (float*)d_out;

  const int n = in_sizes[0] / 5;  // 1048576
  const int B = 256;
  const int gn = (n + B - 1) / B;  // 4096

  // workspace: 16n (xpf) + 2n (pospf) + 4n ints + 33*gn  ≈ 88.5 MB
  float* base = (float*)d_ws;
  i64 off = 0;
  float* xpf      = base + off; off += (i64)16 * n;
  float* pospf    = base + off; off += (i64)2 * n;
  int*   partner1 = (int*)(base + off); off += n;
  int*   c1       = (int*)(base + off); off += n;
  int*   deg2f    = (int*)(base + off); off += n;
  int*   partner2 = (int*)(base + off); off += n;
  float* partials = base + off; off += (i64)33 * gn;
  (void)ws_size; (void)n_in; (void)out_size;

  kA_match1<<<gn, B, 0, stream>>>(x, partner1, n);
  kB_pool1<<<gn, B, 0, stream>>>(x, pos, partner1, W1, W1r, b1, c1, xpf, pospf, n);
  kC_deg2<<<gn, B, 0, stream>>>(partner1, c1, deg2f, n);
  kD_match2<<<gn, B, 0, stream>>>(partner1, c1, pospf, deg2f, partner2, n);
  kE_conv2_reduce<<<gn, B, 0, stream>>>(partner1, c1, partner2, xpf, W2, W2r, b2, partials, n);
  k_final<<<1, 256, 0, stream>>>(partials, gn, l1w, l1b, l2w, l2b, out);
}